// Round 1
// baseline (2470.264 us; speedup 1.0000x reference)
//
#include <hip/hip_runtime.h>
#include <hip/hip_bf16.h>

#define B_ 2
#define S_ 2048
#define D_ 2048
#define H_ 8
#define KV_ 2
#define HD_ 256
#define WINDOW_ 512
#define EPS_ 1e-6f

// ---------------------------------------------------------------------------
// Generic fp32 tiled GEMM: C[M,N] = A[M,K] @ B[K,N], row-major.
// Requires M%64==0, N%64==0, K%16==0 (true for all shapes here).
// 64x64 tile per 256-thread block, 4x4 micro-tile per thread, K-tile 16.
// ---------------------------------------------------------------------------
__global__ __launch_bounds__(256) void gemm_tile(const float* __restrict__ A,
                                                 const float* __restrict__ Bm,
                                                 float* __restrict__ C,
                                                 int M, int N, int K) {
    __shared__ float sA[16][64];  // sA[k][m]
    __shared__ float sB[16][64];  // sB[k][n]

    const int t  = threadIdx.x;
    const int tn = t & 15;        // 0..15
    const int tm = t >> 4;        // 0..15
    const int m0 = blockIdx.y * 64;
    const int n0 = blockIdx.x * 64;

    float acc[4][4] = {};

    const int arow = t >> 2;        // 0..63
    const int ak   = (t & 3) * 4;   // 0,4,8,12
    const int bk   = t >> 4;        // 0..15
    const int bn   = (t & 15) * 4;  // 0..60

    for (int k0 = 0; k0 < K; k0 += 16) {
        float4 a4 = *(const float4*)&A[(size_t)(m0 + arow) * K + k0 + ak];
        float4 b4 = *(const float4*)&Bm[(size_t)(k0 + bk) * N + n0 + bn];
        sA[ak + 0][arow] = a4.x;
        sA[ak + 1][arow] = a4.y;
        sA[ak + 2][arow] = a4.z;
        sA[ak + 3][arow] = a4.w;
        *(float4*)&sB[bk][bn] = b4;
        __syncthreads();
#pragma unroll
        for (int k = 0; k < 16; ++k) {
            float4 av4 = *(const float4*)&sA[k][tm * 4];
            float4 bv4 = *(const float4*)&sB[k][tn * 4];
            float av[4] = {av4.x, av4.y, av4.z, av4.w};
            float bv[4] = {bv4.x, bv4.y, bv4.z, bv4.w};
#pragma unroll
            for (int i = 0; i < 4; ++i)
#pragma unroll
                for (int j = 0; j < 4; ++j) acc[i][j] += av[i] * bv[j];
        }
        __syncthreads();
    }

#pragma unroll
    for (int i = 0; i < 4; ++i) {
        *(float4*)&C[(size_t)(m0 + tm * 4 + i) * N + n0 + tn * 4] =
            make_float4(acc[i][0], acc[i][1], acc[i][2], acc[i][3]);
    }
}

// ---------------------------------------------------------------------------
// Fused per-head RMSNorm (+optional weight) + RoPE, in-place.
// One wave per 256-element head row. Rows ordered: Q rows, K rows, V rows.
// ---------------------------------------------------------------------------
__global__ __launch_bounds__(256) void norm_rope_kernel(
    float* __restrict__ Yq, float* __restrict__ Yk, float* __restrict__ Yv,
    const float* __restrict__ cosb, const float* __restrict__ sinb,
    const float* __restrict__ qw, const float* __restrict__ kw) {
    const int gid  = blockIdx.x * blockDim.x + threadIdx.x;
    const int wid  = gid >> 6;
    const int lane = gid & 63;

    const int nq = B_ * S_ * H_;    // 32768
    const int nk = B_ * S_ * KV_;   // 8192

    float* ptr;
    const float* w = nullptr;
    bool rope;
    int b, s;
    if (wid < nq) {
        b = wid / (S_ * H_);
        int r = wid % (S_ * H_);
        s = r / H_;
        int h = r % H_;
        ptr = Yq + ((size_t)(b * S_ + s)) * (H_ * HD_) + h * HD_;
        w = qw;
        rope = true;
    } else if (wid < nq + nk) {
        int idx = wid - nq;
        b = idx / (S_ * KV_);
        int r = idx % (S_ * KV_);
        s = r / KV_;
        int kv = r % KV_;
        ptr = Yk + ((size_t)(b * S_ + s)) * (KV_ * HD_) + kv * HD_;
        w = kw;
        rope = true;
    } else {
        int idx = wid - nq - nk;
        b = idx / (S_ * KV_);
        int r = idx % (S_ * KV_);
        s = r / KV_;
        int kv = r % KV_;
        ptr = Yv + ((size_t)(b * S_ + s)) * (KV_ * HD_) + kv * HD_;
        w = nullptr;
        rope = false;
    }

    float x0 = ptr[lane];
    float x1 = ptr[lane + 64];
    float x2 = ptr[lane + 128];
    float x3 = ptr[lane + 192];
    float ss = x0 * x0 + x1 * x1 + x2 * x2 + x3 * x3;
#pragma unroll
    for (int off = 32; off >= 1; off >>= 1) ss += __shfl_xor(ss, off);
    const float inv = rsqrtf(ss * (1.0f / HD_) + EPS_);
    float y0 = x0 * inv, y1 = x1 * inv, y2 = x2 * inv, y3 = x3 * inv;
    if (w) {
        y0 *= w[lane];
        y1 *= w[lane + 64];
        y2 *= w[lane + 128];
        y3 *= w[lane + 192];
    }
    if (rope) {
        const float* cb = cosb + ((size_t)(b * S_ + s)) * HD_;
        const float* sb = sinb + ((size_t)(b * S_ + s)) * HD_;
        float c0 = cb[lane], c1 = cb[lane + 64], c2 = cb[lane + 128], c3 = cb[lane + 192];
        float s0 = sb[lane], s1 = sb[lane + 64], s2 = sb[lane + 128], s3 = sb[lane + 192];
        // d<128: x*c - x[d+128]*s ; d>=128: x*c + x[d-128]*s
        float o0 = y0 * c0 - y2 * s0;
        float o1 = y1 * c1 - y3 * s1;
        float o2 = y2 * c2 + y0 * s2;
        float o3 = y3 * c3 + y1 * s3;
        y0 = o0; y1 = o1; y2 = o2; y3 = o3;
    }
    ptr[lane]       = y0;
    ptr[lane + 64]  = y1;
    ptr[lane + 128] = y2;
    ptr[lane + 192] = y3;
}

// ---------------------------------------------------------------------------
// Sliding-window causal attention, online softmax, one wave per (b,h,s).
// No 1/sqrt(d) scale (reference has none). Window: j in [s-511, s].
// Writes attn in (b, s, h*HD + d) layout to feed the output GEMM directly.
// ---------------------------------------------------------------------------
__global__ __launch_bounds__(256) void attn_kernel(const float* __restrict__ Yq,
                                                   const float* __restrict__ Yk,
                                                   const float* __restrict__ Yv,
                                                   float* __restrict__ attn) {
    const int gid  = blockIdx.x * blockDim.x + threadIdx.x;
    const int wid  = gid >> 6;
    const int lane = gid & 63;

    const int s  = wid % S_;
    const int bh = wid / S_;
    const int h  = bh % H_;
    const int b  = bh / H_;
    const int kv = h / (H_ / KV_);

    const float* qr = Yq + ((size_t)(b * S_ + s)) * (H_ * HD_) + h * HD_;
    const float q0 = qr[lane];
    const float q1 = qr[lane + 64];
    const float q2 = qr[lane + 128];
    const float q3 = qr[lane + 192];

    int j0 = s - (WINDOW_ - 1);
    if (j0 < 0) j0 = 0;

    float m = -1e30f, l = 0.0f;
    float a0 = 0.0f, a1 = 0.0f, a2 = 0.0f, a3 = 0.0f;

    for (int j = j0; j <= s; ++j) {
        const float* kr = Yk + ((size_t)(b * S_ + j)) * (KV_ * HD_) + kv * HD_;
        const float* vr = Yv + ((size_t)(b * S_ + j)) * (KV_ * HD_) + kv * HD_;
        float t = q0 * kr[lane] + q1 * kr[lane + 64] + q2 * kr[lane + 128] + q3 * kr[lane + 192];
#pragma unroll
        for (int off = 32; off >= 1; off >>= 1) t += __shfl_xor(t, off);
        const float nm = fmaxf(m, t);
        const float sc = __expf(m - nm);
        const float p  = __expf(t - nm);
        l = l * sc + p;
        a0 = a0 * sc + p * vr[lane];
        a1 = a1 * sc + p * vr[lane + 64];
        a2 = a2 * sc + p * vr[lane + 128];
        a3 = a3 * sc + p * vr[lane + 192];
        m = nm;
    }

    const float invl = 1.0f / l;
    float* o = attn + ((size_t)(b * S_ + s)) * (H_ * HD_) + h * HD_;
    o[lane]       = a0 * invl;
    o[lane + 64]  = a1 * invl;
    o[lane + 128] = a2 * invl;
    o[lane + 192] = a3 * invl;
}

// ---------------------------------------------------------------------------
extern "C" void kernel_launch(void* const* d_in, const int* in_sizes, int n_in,
                              void* d_out, int out_size, void* d_ws, size_t ws_size,
                              hipStream_t stream) {
    const float* x    = (const float*)d_in[0];  // (B,S,D)
    const float* cosb = (const float*)d_in[1];  // (B,S,HD)
    const float* sinb = (const float*)d_in[2];  // (B,S,HD)
    // d_in[3]: attention_mask — replaced by analytic sliding window
    const float* wq = (const float*)d_in[4];  // (D, H*HD)
    const float* wk = (const float*)d_in[5];  // (D, KV*HD)
    const float* wv = (const float*)d_in[6];  // (D, KV*HD)
    const float* wo = (const float*)d_in[7];  // (H*HD, D)
    const float* qw = (const float*)d_in[8];  // (HD,)
    const float* kw = (const float*)d_in[9];  // (HD,)
    float* out = (float*)d_out;

    float* ws   = (float*)d_ws;
    float* Yq   = ws;                                    // B*S*H*HD   = 8388608 f
    float* Yk   = Yq + (size_t)B_ * S_ * H_ * HD_;       // B*S*KV*HD  = 2097152 f
    float* Yv   = Yk + (size_t)B_ * S_ * KV_ * HD_;      // B*S*KV*HD  = 2097152 f
    float* attn = Yv + (size_t)B_ * S_ * KV_ * HD_;      // B*S*H*HD   = 8388608 f
    // total ws use: ~84 MB

    const int M = B_ * S_;  // 4096
    dim3 blk(256);

    // QKV projections
    gemm_tile<<<dim3((H_ * HD_) / 64, M / 64), blk, 0, stream>>>(x, wq, Yq, M, H_ * HD_, D_);
    gemm_tile<<<dim3((KV_ * HD_) / 64, M / 64), blk, 0, stream>>>(x, wk, Yk, M, KV_ * HD_, D_);
    gemm_tile<<<dim3((KV_ * HD_) / 64, M / 64), blk, 0, stream>>>(x, wv, Yv, M, KV_ * HD_, D_);

    // RMSNorm + RoPE (in-place): (B*S*H + B*S*KV + B*S*KV) rows = 49152 waves
    norm_rope_kernel<<<(B_ * S_ * (H_ + 2 * KV_) * 64) / 256, blk, 0, stream>>>(
        Yq, Yk, Yv, cosb, sinb, qw, kw);

    // Attention: one wave per (b,h,s) = 32768 waves
    attn_kernel<<<(B_ * H_ * S_ * 64) / 256, blk, 0, stream>>>(Yq, Yk, Yv, attn);

    // Output projection
    gemm_tile<<<dim3(D_ / 64, M / 64), blk, 0, stream>>>(attn, wo, out, M, D_, H_ * HD_);
}

// Round 2
// 407.918 us; speedup vs baseline: 6.0558x; 6.0558x over previous
//
#include <hip/hip_runtime.h>
#include <hip/hip_bf16.h>
#include <hip/hip_fp16.h>

#define B_ 2
#define S_ 2048
#define D_ 2048
#define H_ 8
#define KV_ 2
#define HD_ 256
#define WINDOW_ 512
#define EPS_ 1e-6f
#define MASKV_ -30000.0f

typedef _Float16 f16;
typedef _Float16 half8 __attribute__((ext_vector_type(8)));
typedef _Float16 half4v __attribute__((ext_vector_type(4)));
typedef float floatx4 __attribute__((ext_vector_type(4)));

#define GLOAD_LDS16(g, l)                                                        \
    __builtin_amdgcn_global_load_lds(                                            \
        (const __attribute__((address_space(1))) unsigned int*)(g),              \
        (__attribute__((address_space(3))) unsigned int*)(l), 16, 0, 0)

// ---------------------------------------------------------------------------
// fp32 -> fp16 elementwise convert (4 per thread)
// ---------------------------------------------------------------------------
__global__ __launch_bounds__(256) void convert_x(const float* __restrict__ src,
                                                 f16* __restrict__ dst) {
    const int i = blockIdx.x * 256 + threadIdx.x;
    float4 v = ((const float4*)src)[i];
    half4v h = {(f16)v.x, (f16)v.y, (f16)v.z, (f16)v.w};
    ((half4v*)dst)[i] = h;
}

// ---------------------------------------------------------------------------
// fp32 [R][C] -> fp16 [C][R] transpose+convert (weights, one-time)
// block (32,8), grid (C/32, R/32)
// ---------------------------------------------------------------------------
__global__ __launch_bounds__(256) void transpose_convert(const float* __restrict__ src,
                                                         f16* __restrict__ dst,
                                                         int R, int C) {
    __shared__ float tile[32][33];
    const int tx = threadIdx.x, ty = threadIdx.y;
    const int c0 = blockIdx.x * 32, r0 = blockIdx.y * 32;
#pragma unroll
    for (int i = 0; i < 4; ++i)
        tile[ty + i * 8][tx] = src[(size_t)(r0 + ty + i * 8) * C + c0 + tx];
    __syncthreads();
#pragma unroll
    for (int i = 0; i < 4; ++i)
        dst[(size_t)(c0 + ty + i * 8) * R + r0 + tx] = (f16)tile[tx][ty + i * 8];
}

// ---------------------------------------------------------------------------
// fp16 MFMA GEMM: C[M,N] = A[M,K] @ BT[N,K]^T.  128x128 tile, BK=32,
// 4 waves (2x2 of 64x64), 16x16x32 MFMA, global_load_lds staging with
// XOR group swizzle (g' = (g + (row>>1)) & 3) to break bank conflicts.
// ---------------------------------------------------------------------------
template <typename OutT>
__global__ __launch_bounds__(256) void gemm_f16(const f16* __restrict__ A,
                                                const f16* __restrict__ BT,
                                                OutT* __restrict__ C,
                                                int M, int N, int K) {
    __shared__ __align__(16) f16 sA[128 * 32];
    __shared__ __align__(16) f16 sB[128 * 32];

    const int t = threadIdx.x;
    const int lane = t & 63;
    const int w = t >> 6;
    const int i16 = lane & 15, q4 = lane >> 4;
    const int m0 = blockIdx.y * 128, n0 = blockIdx.x * 128;
    const int mw = (w & 1) * 64, nw = (w >> 1) * 64;

    floatx4 acc[16];
#pragma unroll
    for (int i = 0; i < 16; ++i) acc[i] = (floatx4){0.f, 0.f, 0.f, 0.f};

    const int srow = (w * 2) * 16 + (lane >> 2);   // staging row base for chunk c=0
    const int sgp = lane & 3;

    for (int k0 = 0; k0 < K; k0 += 32) {
#pragma unroll
        for (int c = 0; c < 2; ++c) {
            const int chunk = w * 2 + c;
            const int row = srow + c * 16;
            const int g = (sgp - (row >> 1)) & 3;
            GLOAD_LDS16(A + (size_t)(m0 + row) * K + k0 + g * 8,
                        sA + chunk * 512 + lane * 8);
            GLOAD_LDS16(BT + (size_t)(n0 + row) * K + k0 + g * 8,
                        sB + chunk * 512 + lane * 8);
        }
        __syncthreads();

        half8 af[4], bf[4];
#pragma unroll
        for (int mi = 0; mi < 4; ++mi) {
            const int row = mw + mi * 16 + i16;
            const int gp = (q4 + (row >> 1)) & 3;
            af[mi] = *(const half8*)(sA + row * 32 + gp * 8);
        }
#pragma unroll
        for (int ni = 0; ni < 4; ++ni) {
            const int row = nw + ni * 16 + i16;
            const int gp = (q4 + (row >> 1)) & 3;
            bf[ni] = *(const half8*)(sB + row * 32 + gp * 8);
        }
#pragma unroll
        for (int mi = 0; mi < 4; ++mi)
#pragma unroll
            for (int ni = 0; ni < 4; ++ni)
                acc[mi * 4 + ni] = __builtin_amdgcn_mfma_f32_16x16x32_f16(
                    af[mi], bf[ni], acc[mi * 4 + ni], 0, 0, 0);
        __syncthreads();
    }

#pragma unroll
    for (int mi = 0; mi < 4; ++mi)
#pragma unroll
        for (int ni = 0; ni < 4; ++ni)
#pragma unroll
            for (int r = 0; r < 4; ++r) {
                const int row = m0 + mw + mi * 16 + q4 * 4 + r;
                const int col = n0 + nw + ni * 16 + i16;
                C[(size_t)row * N + col] = (OutT)acc[mi * 4 + ni][r];
            }
}

// ---------------------------------------------------------------------------
// Fused per-head RMSNorm + RoPE on fp16, one wave per 256-elem head row.
// Q: in-place on Qh [b*S+s][h*256+d].
// K: KVh[.., kv*256+d] -> Kh[(b*KV+kv)][s][d]  (+kw, +rope)
// V: KVh[.., 512+kv*256+d] -> Vt[(b*KV+kv)][d][s]  (transposed, no weight)
// ---------------------------------------------------------------------------
__global__ __launch_bounds__(256) void norm_rope_f16(
    f16* __restrict__ Qh, const f16* __restrict__ KVh,
    f16* __restrict__ Kh, f16* __restrict__ Vt,
    const float* __restrict__ cosb, const float* __restrict__ sinb,
    const float* __restrict__ qw, const float* __restrict__ kw) {
    const int gid = blockIdx.x * 256 + threadIdx.x;
    const int wid = gid >> 6, lane = gid & 63;
    const int nq = B_ * S_ * H_;
    const int nk = B_ * S_ * KV_;

    float x0, x1, x2, x3;
    int b, s;

    if (wid < nq) {
        b = wid / (S_ * H_);
        const int r = wid % (S_ * H_);
        s = r / H_;
        const int h = r % H_;
        f16* p = Qh + (size_t)(b * S_ + s) * (H_ * HD_) + h * HD_;
        x0 = (float)p[lane];       x1 = (float)p[lane + 64];
        x2 = (float)p[lane + 128]; x3 = (float)p[lane + 192];
        float ss = x0 * x0 + x1 * x1 + x2 * x2 + x3 * x3;
#pragma unroll
        for (int off = 32; off >= 1; off >>= 1) ss += __shfl_xor(ss, off);
        const float inv = rsqrtf(ss * (1.0f / HD_) + EPS_);
        float y0 = x0 * inv * qw[lane], y1 = x1 * inv * qw[lane + 64];
        float y2 = x2 * inv * qw[lane + 128], y3 = x3 * inv * qw[lane + 192];
        const float* cb = cosb + (size_t)(b * S_ + s) * HD_;
        const float* sb = sinb + (size_t)(b * S_ + s) * HD_;
        float o0 = y0 * cb[lane] - y2 * sb[lane];
        float o1 = y1 * cb[lane + 64] - y3 * sb[lane + 64];
        float o2 = y2 * cb[lane + 128] + y0 * sb[lane + 128];
        float o3 = y3 * cb[lane + 192] + y1 * sb[lane + 192];
        p[lane] = (f16)o0; p[lane + 64] = (f16)o1;
        p[lane + 128] = (f16)o2; p[lane + 192] = (f16)o3;
    } else if (wid < nq + nk) {
        const int idx = wid - nq;
        b = idx / (S_ * KV_);
        const int r = idx % (S_ * KV_);
        s = r / KV_;
        const int kv = r % KV_;
        const f16* p = KVh + (size_t)(b * S_ + s) * (2 * KV_ * HD_) + kv * HD_;
        x0 = (float)p[lane];       x1 = (float)p[lane + 64];
        x2 = (float)p[lane + 128]; x3 = (float)p[lane + 192];
        float ss = x0 * x0 + x1 * x1 + x2 * x2 + x3 * x3;
#pragma unroll
        for (int off = 32; off >= 1; off >>= 1) ss += __shfl_xor(ss, off);
        const float inv = rsqrtf(ss * (1.0f / HD_) + EPS_);
        float y0 = x0 * inv * kw[lane], y1 = x1 * inv * kw[lane + 64];
        float y2 = x2 * inv * kw[lane + 128], y3 = x3 * inv * kw[lane + 192];
        const float* cb = cosb + (size_t)(b * S_ + s) * HD_;
        const float* sb = sinb + (size_t)(b * S_ + s) * HD_;
        float o0 = y0 * cb[lane] - y2 * sb[lane];
        float o1 = y1 * cb[lane + 64] - y3 * sb[lane + 64];
        float o2 = y2 * cb[lane + 128] + y0 * sb[lane + 128];
        float o3 = y3 * cb[lane + 192] + y1 * sb[lane + 192];
        f16* d = Kh + ((size_t)(b * KV_ + kv) * S_ + s) * HD_;
        d[lane] = (f16)o0; d[lane + 64] = (f16)o1;
        d[lane + 128] = (f16)o2; d[lane + 192] = (f16)o3;
    } else {
        const int idx = wid - nq - nk;
        b = idx / (S_ * KV_);
        const int r = idx % (S_ * KV_);
        s = r / KV_;
        const int kv = r % KV_;
        const f16* p = KVh + (size_t)(b * S_ + s) * (2 * KV_ * HD_) + KV_ * HD_ + kv * HD_;
        x0 = (float)p[lane];       x1 = (float)p[lane + 64];
        x2 = (float)p[lane + 128]; x3 = (float)p[lane + 192];
        float ss = x0 * x0 + x1 * x1 + x2 * x2 + x3 * x3;
#pragma unroll
        for (int off = 32; off >= 1; off >>= 1) ss += __shfl_xor(ss, off);
        const float inv = rsqrtf(ss * (1.0f / HD_) + EPS_);
        f16* d = Vt + (size_t)(b * KV_ + kv) * HD_ * S_;
        d[(size_t)(lane)*S_ + s]       = (f16)(x0 * inv);
        d[(size_t)(lane + 64) * S_ + s]  = (f16)(x1 * inv);
        d[(size_t)(lane + 128) * S_ + s] = (f16)(x2 * inv);
        d[(size_t)(lane + 192) * S_ + s] = (f16)(x3 * inv);
    }
}

// ---------------------------------------------------------------------------
// MFMA flash attention. Block = (qt, h, b): 64 queries, 4 waves x 16 queries.
// K-tiles of 64 keys staged in LDS (XOR-swizzled for conflict-free b128).
// Online softmax; P round-trips through padded LDS (C-layout -> A-layout).
// ---------------------------------------------------------------------------
__global__ __launch_bounds__(256) void attn_mfma(const f16* __restrict__ Qh,
                                                 const f16* __restrict__ Kh,
                                                 const f16* __restrict__ Vt,
                                                 f16* __restrict__ attnh) {
    __shared__ __align__(16) f16 sK[64 * 256];   // [key][dim], 16B-group swizzle by key
    __shared__ __align__(16) f16 sV[256 * 64];   // [dim][key], 16B-group swizzle by dim
    __shared__ __align__(16) f16 sP[4][16 * 72]; // per-wave P, padded stride 72

    const int qt = blockIdx.x, h = blockIdx.y, b = blockIdx.z;
    const int kvh = h / (H_ / KV_);
    const int t = threadIdx.x, lane = t & 63, w = t >> 6;
    const int i16 = lane & 15, q4 = lane >> 4;

    // Q fragments (A-layout): query m = i16, dims k = kk*32 + q4*8 + j
    const int qrow = qt * 64 + w * 16 + i16;
    const f16* qbase = Qh + (size_t)(b * S_ + qrow) * (H_ * HD_) + h * HD_ + q4 * 8;
    half8 qf[8];
#pragma unroll
    for (int kk = 0; kk < 8; ++kk) qf[kk] = *(const half8*)(qbase + kk * 32);

    floatx4 o[16];
#pragma unroll
    for (int i = 0; i < 16; ++i) o[i] = (floatx4){0.f, 0.f, 0.f, 0.f};
    float mrow[4] = {-1e30f, -1e30f, -1e30f, -1e30f};
    float lrow[4] = {0.f, 0.f, 0.f, 0.f};

    const size_t kbase = (size_t)(b * KV_ + kvh) * S_ * HD_;
    const size_t vbase = (size_t)(b * KV_ + kvh) * HD_ * S_;
    const int srow0 = qt * 64 + w * 16 + q4 * 4;

    const int kt_lo = qt >= 8 ? qt - 8 : 0;
    for (int kt = kt_lo; kt <= qt; ++kt) {
        // ---- stage K (32KB) + V (32KB): 32 chunks each, 8 per wave ----
#pragma unroll
        for (int c = 0; c < 8; ++c) {
            const int chunk = w * 8 + c;
            const int keyl = chunk * 2 + (lane >> 5);
            const int g = (lane & 31) ^ (keyl & 31);
            GLOAD_LDS16(Kh + kbase + (size_t)(kt * 64 + keyl) * HD_ + g * 8,
                        sK + chunk * 512 + lane * 8);
            const int diml = chunk * 8 + (lane >> 3);
            const int g2 = (lane & 7) ^ (diml & 7);
            GLOAD_LDS16(Vt + vbase + (size_t)diml * S_ + kt * 64 + g2 * 8,
                        sV + chunk * 512 + lane * 8);
        }
        __syncthreads();

        // ---- QK^T: scores[16q x 64k] per wave ----
        floatx4 sc[4];
#pragma unroll
        for (int nt = 0; nt < 4; ++nt) sc[nt] = (floatx4){0.f, 0.f, 0.f, 0.f};
#pragma unroll
        for (int ks = 0; ks < 8; ++ks)
#pragma unroll
            for (int nt = 0; nt < 4; ++nt) {
                const int keyl = nt * 16 + i16;
                const int gp = (ks * 4 + q4) ^ (keyl & 31);
                half8 kf = *(const half8*)(sK + keyl * 256 + gp * 8);
                sc[nt] = __builtin_amdgcn_mfma_f32_16x16x32_f16(qf[ks], kf, sc[nt], 0, 0, 0);
            }

        // ---- mask + online softmax (rows r = srow0..srow0+3) ----
#pragma unroll
        for (int r = 0; r < 4; ++r) {
            const int s = srow0 + r;
            float mx = -1e30f;
#pragma unroll
            for (int nt = 0; nt < 4; ++nt) {
                const int j = kt * 64 + nt * 16 + i16;
                const bool valid = (j <= s) && (s - j < WINDOW_);
                const float v = valid ? sc[nt][r] : MASKV_;
                sc[nt][r] = v;
                mx = fmaxf(mx, v);
            }
#pragma unroll
            for (int off = 1; off < 16; off <<= 1) mx = fmaxf(mx, __shfl_xor(mx, off));
            const float mnew = fmaxf(mrow[r], mx);
            const float alpha = __expf(mrow[r] - mnew);
            mrow[r] = mnew;
            float rs = 0.f;
#pragma unroll
            for (int nt = 0; nt < 4; ++nt) {
                const float p = __expf(sc[nt][r] - mnew);
                sc[nt][r] = p;
                rs += p;
            }
#pragma unroll
            for (int off = 1; off < 16; off <<= 1) rs += __shfl_xor(rs, off);
            lrow[r] = lrow[r] * alpha + rs;
#pragma unroll
            for (int nt2 = 0; nt2 < 16; ++nt2) o[nt2][r] *= alpha;
        }

        // ---- P: C-layout -> LDS -> A-layout (wave-local) ----
        f16* sPw = sP[w];
#pragma unroll
        for (int nt = 0; nt < 4; ++nt)
#pragma unroll
            for (int r = 0; r < 4; ++r)
                sPw[(q4 * 4 + r) * 72 + nt * 16 + i16] = (f16)sc[nt][r];
        asm volatile("s_waitcnt lgkmcnt(0)" ::: "memory");

        // ---- PV: o[16q x 256d] += P[16q x 64k] @ V[64k x 256d] ----
#pragma unroll
        for (int kt2 = 0; kt2 < 2; ++kt2) {
            half8 pf = *(const half8*)(sPw + i16 * 72 + kt2 * 32 + q4 * 8);
#pragma unroll
            for (int nt2 = 0; nt2 < 16; ++nt2) {
                const int dim = nt2 * 16 + i16;
                const int gp = (kt2 * 4 + q4) ^ (dim & 7);
                half8 vf = *(const half8*)(sV + dim * 64 + gp * 8);
                o[nt2] = __builtin_amdgcn_mfma_f32_16x16x32_f16(pf, vf, o[nt2], 0, 0, 0);
            }
        }
        __syncthreads();
    }

    // ---- epilogue ----
    float inv[4];
#pragma unroll
    for (int r = 0; r < 4; ++r) inv[r] = 1.0f / lrow[r];
    f16* ob = attnh + (size_t)(b * S_ + qt * 64 + w * 16) * (H_ * HD_) + h * HD_;
#pragma unroll
    for (int nt2 = 0; nt2 < 16; ++nt2)
#pragma unroll
        for (int r = 0; r < 4; ++r)
            ob[(size_t)(q4 * 4 + r) * (H_ * HD_) + nt2 * 16 + i16] =
                (f16)(o[nt2][r] * inv[r]);
}

// ---------------------------------------------------------------------------
extern "C" void kernel_launch(void* const* d_in, const int* in_sizes, int n_in,
                              void* d_out, int out_size, void* d_ws, size_t ws_size,
                              hipStream_t stream) {
    const float* x    = (const float*)d_in[0];
    const float* cosb = (const float*)d_in[1];
    const float* sinb = (const float*)d_in[2];
    const float* wq = (const float*)d_in[4];
    const float* wk = (const float*)d_in[5];
    const float* wv = (const float*)d_in[6];
    const float* wo = (const float*)d_in[7];
    const float* qw = (const float*)d_in[8];
    const float* kw = (const float*)d_in[9];
    float* out = (float*)d_out;

    f16* ws = (f16*)d_ws;
    f16* xh   = ws;                    // 8388608 halves (reused as attnh later)
    f16* wqT  = xh + 8388608;          // 4194304
    f16* wkvT = wqT + 4194304;         // 2097152
    f16* woT  = wkvT + 2097152;        // 4194304
    f16* Qh   = woT + 4194304;         // 8388608
    f16* KVh  = Qh + 8388608;          // 4194304
    f16* Kh   = KVh + 4194304;         // 2097152
    f16* Vt   = Kh + 2097152;          // 2097152
    f16* attnh = xh;                   // alias: xh dead after QKV GEMMs

    const int M = B_ * S_;  // 4096

    // 1) converts / weight transposes
    convert_x<<<(B_ * S_ * D_) / 1024, 256, 0, stream>>>(x, xh);
    transpose_convert<<<dim3(64, 64), dim3(32, 8), 0, stream>>>(wq, wqT, D_, H_ * HD_);
    transpose_convert<<<dim3(16, 64), dim3(32, 8), 0, stream>>>(wk, wkvT, D_, KV_ * HD_);
    transpose_convert<<<dim3(16, 64), dim3(32, 8), 0, stream>>>(wv, wkvT + (size_t)512 * 2048, D_, KV_ * HD_);
    transpose_convert<<<dim3(64, 64), dim3(32, 8), 0, stream>>>(wo, woT, H_ * HD_, D_);

    // 2) projections (fp16 MFMA)
    gemm_f16<f16><<<dim3(16, 32), 256, 0, stream>>>(xh, wqT, Qh, M, H_ * HD_, D_);
    gemm_f16<f16><<<dim3(8, 32), 256, 0, stream>>>(xh, wkvT, KVh, M, 2 * KV_ * HD_, D_);

    // 3) RMSNorm + RoPE (+V transpose)
    norm_rope_f16<<<(B_ * S_ * (H_ + 2 * KV_) * 64) / 256, 256, 0, stream>>>(
        Qh, KVh, Kh, Vt, cosb, sinb, qw, kw);

    // 4) flash attention
    attn_mfma<<<dim3(S_ / 64, H_, B_), 256, 0, stream>>>(Qh, Kh, Vt, attnh);

    // 5) output projection (fp32 out)
    gemm_f16<float><<<dim3(16, 32), 256, 0, stream>>>(attnh, woT, out, M, D_, H_ * HD_);
}

// Round 4
// 333.756 us; speedup vs baseline: 7.4014x; 1.2222x over previous
//
#include <hip/hip_runtime.h>
#include <hip/hip_bf16.h>
#include <hip/hip_fp16.h>

#define B_ 2
#define S_ 2048
#define D_ 2048
#define H_ 8
#define KV_ 2
#define HD_ 256
#define WINDOW_ 512
#define EPS_ 1e-6f
#define MASKV_ -30000.0f

typedef _Float16 f16;
typedef _Float16 half8 __attribute__((ext_vector_type(8)));
typedef _Float16 half2v __attribute__((ext_vector_type(2)));
typedef float floatx4 __attribute__((ext_vector_type(4)));

#define GLOAD_LDS16(g, l)                                                        \
    __builtin_amdgcn_global_load_lds(                                            \
        (const __attribute__((address_space(1))) unsigned int*)(g),              \
        (__attribute__((address_space(3))) unsigned int*)(l), 16, 0, 0)

// ---------------------------------------------------------------------------
// prep: fp32->fp16 convert of x  +  all 4 weight transposes, one dispatch.
// ---------------------------------------------------------------------------
__global__ __launch_bounds__(256) void prep(const float* __restrict__ x,
                                            const float* __restrict__ wq,
                                            const float* __restrict__ wk,
                                            const float* __restrict__ wv,
                                            const float* __restrict__ wo,
                                            f16* __restrict__ xh,
                                            f16* __restrict__ BT,
                                            f16* __restrict__ woT) {
    int bid = blockIdx.x;
    const int t = threadIdx.x;
    if (bid < 8192) {
        const int i = bid * 256 + t;
        float4 v = ((const float4*)x)[i];
        typedef _Float16 half4v __attribute__((ext_vector_type(4)));
        half4v hv = {(f16)v.x, (f16)v.y, (f16)v.z, (f16)v.w};
        ((half4v*)xh)[i] = hv;
        return;
    }
    bid -= 8192;
    const float* src;
    f16* dst;
    int C, bx, by;
    if (bid < 4096) {
        src = wq; dst = BT; C = 2048; bx = bid & 63; by = bid >> 6;
    } else if (bid < 5120) {
        const int b2 = bid - 4096;
        src = wk; dst = BT + (size_t)2048 * 2048; C = 512; bx = b2 & 15; by = b2 >> 4;
    } else if (bid < 6144) {
        const int b2 = bid - 5120;
        src = wv; dst = BT + (size_t)2560 * 2048; C = 512; bx = b2 & 15; by = b2 >> 4;
    } else {
        const int b2 = bid - 6144;
        src = wo; dst = woT; C = 2048; bx = b2 & 63; by = b2 >> 6;
    }
    __shared__ float tile[32][33];
    const int tx = t & 31, ty = t >> 5;  // 32 x 8
    const int c0 = bx * 32, r0 = by * 32;
#pragma unroll
    for (int i = 0; i < 4; ++i)
        tile[ty + i * 8][tx] = src[(size_t)(r0 + ty + i * 8) * C + c0 + tx];
    __syncthreads();
#pragma unroll
    for (int i = 0; i < 4; ++i)
        dst[(size_t)(c0 + ty + i * 8) * 2048 + r0 + tx] = (f16)tile[tx][ty + i * 8];
}

// ---------------------------------------------------------------------------
// fp16 MFMA GEMM: C[M,N] = A[M,K] @ BT[N,K]^T.  128x128 tile, BK=32,
// 4 waves (2x2 of 64x64), 16x16x32 MFMA, global_load_lds staging with
// XOR group swizzle to keep LDS fragment reads 2-way (free).
// ---------------------------------------------------------------------------
template <typename OutT>
__global__ __launch_bounds__(256) void gemm_f16(const f16* __restrict__ A,
                                                const f16* __restrict__ BT,
                                                OutT* __restrict__ C,
                                                int M, int N, int K) {
    __shared__ __align__(16) f16 sA[128 * 32];
    __shared__ __align__(16) f16 sB[128 * 32];

    const int t = threadIdx.x;
    const int lane = t & 63;
    const int w = t >> 6;
    const int i16 = lane & 15, q4 = lane >> 4;
    const int m0 = blockIdx.y * 128, n0 = blockIdx.x * 128;
    const int mw = (w & 1) * 64, nw = (w >> 1) * 64;

    floatx4 acc[16];
#pragma unroll
    for (int i = 0; i < 16; ++i) acc[i] = (floatx4){0.f, 0.f, 0.f, 0.f};

    const int srow = w * 32 + (lane >> 2);
    const int sgp = lane & 3;

    for (int k0 = 0; k0 < K; k0 += 32) {
#pragma unroll
        for (int c = 0; c < 2; ++c) {
            const int chunk = w * 2 + c;
            const int row = srow + c * 16;
            const int g = (sgp - (row >> 1)) & 3;
            GLOAD_LDS16(A + (size_t)(m0 + row) * K + k0 + g * 8,
                        sA + chunk * 512 + lane * 8);
            GLOAD_LDS16(BT + (size_t)(n0 + row) * K + k0 + g * 8,
                        sB + chunk * 512 + lane * 8);
        }
        __syncthreads();

        half8 af[4], bf[4];
#pragma unroll
        for (int mi = 0; mi < 4; ++mi) {
            const int row = mw + mi * 16 + i16;
            const int gp = (q4 + (row >> 1)) & 3;
            af[mi] = *(const half8*)(sA + row * 32 + gp * 8);
        }
#pragma unroll
        for (int ni = 0; ni < 4; ++ni) {
            const int row = nw + ni * 16 + i16;
            const int gp = (q4 + (row >> 1)) & 3;
            bf[ni] = *(const half8*)(sB + row * 32 + gp * 8);
        }
#pragma unroll
        for (int mi = 0; mi < 4; ++mi)
#pragma unroll
            for (int ni = 0; ni < 4; ++ni)
                acc[mi * 4 + ni] = __builtin_amdgcn_mfma_f32_16x16x32_f16(
                    af[mi], bf[ni], acc[mi * 4 + ni], 0, 0, 0);
        __syncthreads();
    }

#pragma unroll
    for (int mi = 0; mi < 4; ++mi)
#pragma unroll
        for (int ni = 0; ni < 4; ++ni)
#pragma unroll
            for (int r = 0; r < 4; ++r) {
                const int row = m0 + mw + mi * 16 + q4 * 4 + r;
                const int col = n0 + nw + ni * 16 + i16;
                C[(size_t)row * N + col] = (OutT)acc[mi * 4 + ni][r];
            }
}

// ---------------------------------------------------------------------------
// Fused per-head RMSNorm + RoPE on fp16 QKVh [b*S+s][3072].
// Q (cols 0..2047): in-place. K (2048+kv*256): -> Kh[(b*KV+kv)][s][d].
// V (2560+kv*256): -> Vt[(b*KV+kv)][d][s] (transposed, no weight).
// ---------------------------------------------------------------------------
__global__ __launch_bounds__(256) void norm_rope_f16(
    f16* __restrict__ QKVh, f16* __restrict__ Kh, f16* __restrict__ Vt,
    const float* __restrict__ cosb, const float* __restrict__ sinb,
    const float* __restrict__ qw, const float* __restrict__ kw) {
    const int gid = blockIdx.x * 256 + threadIdx.x;
    const int wid = gid >> 6, lane = gid & 63;
    const int nq = B_ * S_ * H_;
    const int nk = B_ * S_ * KV_;
    const int d0 = lane * 2;

    if (wid < nq) {
        const int b = wid / (S_ * H_);
        const int r = wid % (S_ * H_);
        const int s = r / H_, h = r % H_;
        f16* p = QKVh + (size_t)(b * S_ + s) * 3072 + h * HD_;
        half2v lo = *(const half2v*)(p + d0);
        half2v hi = *(const half2v*)(p + 128 + d0);
        float x0 = (float)lo[0], x1 = (float)lo[1], x2 = (float)hi[0], x3 = (float)hi[1];
        float ss = x0 * x0 + x1 * x1 + x2 * x2 + x3 * x3;
#pragma unroll
        for (int off = 32; off >= 1; off >>= 1) ss += __shfl_xor(ss, off);
        const float inv = rsqrtf(ss * (1.0f / HD_) + EPS_);
        float2 wlo = *(const float2*)(qw + d0), whi = *(const float2*)(qw + 128 + d0);
        float y0 = x0 * inv * wlo.x, y1 = x1 * inv * wlo.y;
        float y2 = x2 * inv * whi.x, y3 = x3 * inv * whi.y;
        const float* cb = cosb + (size_t)(b * S_ + s) * HD_;
        const float* sb = sinb + (size_t)(b * S_ + s) * HD_;
        float2 clo = *(const float2*)(cb + d0), chi = *(const float2*)(cb + 128 + d0);
        float2 slo = *(const float2*)(sb + d0), shi = *(const float2*)(sb + 128 + d0);
        half2v olo = {(f16)(y0 * clo.x - y2 * slo.x), (f16)(y1 * clo.y - y3 * slo.y)};
        half2v ohi = {(f16)(y2 * chi.x + y0 * shi.x), (f16)(y3 * chi.y + y1 * shi.y)};
        *(half2v*)(p + d0) = olo;
        *(half2v*)(p + 128 + d0) = ohi;
    } else if (wid < nq + nk) {
        const int idx = wid - nq;
        const int b = idx / (S_ * KV_);
        const int r = idx % (S_ * KV_);
        const int s = r / KV_, kv = r % KV_;
        const f16* p = QKVh + (size_t)(b * S_ + s) * 3072 + 2048 + kv * HD_;
        half2v lo = *(const half2v*)(p + d0);
        half2v hi = *(const half2v*)(p + 128 + d0);
        float x0 = (float)lo[0], x1 = (float)lo[1], x2 = (float)hi[0], x3 = (float)hi[1];
        float ss = x0 * x0 + x1 * x1 + x2 * x2 + x3 * x3;
#pragma unroll
        for (int off = 32; off >= 1; off >>= 1) ss += __shfl_xor(ss, off);
        const float inv = rsqrtf(ss * (1.0f / HD_) + EPS_);
        float2 wlo = *(const float2*)(kw + d0), whi = *(const float2*)(kw + 128 + d0);
        float y0 = x0 * inv * wlo.x, y1 = x1 * inv * wlo.y;
        float y2 = x2 * inv * whi.x, y3 = x3 * inv * whi.y;
        const float* cb = cosb + (size_t)(b * S_ + s) * HD_;
        const float* sb = sinb + (size_t)(b * S_ + s) * HD_;
        float2 clo = *(const float2*)(cb + d0), chi = *(const float2*)(cb + 128 + d0);
        float2 slo = *(const float2*)(sb + d0), shi = *(const float2*)(sb + 128 + d0);
        half2v olo = {(f16)(y0 * clo.x - y2 * slo.x), (f16)(y1 * clo.y - y3 * slo.y)};
        half2v ohi = {(f16)(y2 * chi.x + y0 * shi.x), (f16)(y3 * chi.y + y1 * shi.y)};
        f16* d = Kh + ((size_t)(b * KV_ + kv) * S_ + s) * HD_;
        *(half2v*)(d + d0) = olo;
        *(half2v*)(d + 128 + d0) = ohi;
    } else {
        const int idx = wid - nq - nk;
        const int b = idx / (S_ * KV_);
        const int r = idx % (S_ * KV_);
        const int s = r / KV_, kv = r % KV_;
        const f16* p = QKVh + (size_t)(b * S_ + s) * 3072 + 2560 + kv * HD_;
        half2v lo = *(const half2v*)(p + d0);
        half2v hi = *(const half2v*)(p + 128 + d0);
        float x0 = (float)lo[0], x1 = (float)lo[1], x2 = (float)hi[0], x3 = (float)hi[1];
        float ss = x0 * x0 + x1 * x1 + x2 * x2 + x3 * x3;
#pragma unroll
        for (int off = 32; off >= 1; off >>= 1) ss += __shfl_xor(ss, off);
        const float inv = rsqrtf(ss * (1.0f / HD_) + EPS_);
        f16* d = Vt + (size_t)(b * KV_ + kv) * HD_ * S_;
        d[(size_t)d0 * S_ + s] = (f16)(x0 * inv);
        d[(size_t)(d0 + 1) * S_ + s] = (f16)(x1 * inv);
        d[(size_t)(d0 + 128) * S_ + s] = (f16)(x2 * inv);
        d[(size_t)(d0 + 129) * S_ + s] = (f16)(x3 * inv);
    }
}

// ---------------------------------------------------------------------------
// MFMA flash attention v2. Block = (qt, h, b): 128 queries, 8 waves x 16 q.
// Double-buffered K/V LDS staging; one barrier per K-tile step.
// Tile range: first in-window key for s=128qt is 128qt-511, in tile
// (128qt-511)>>6 = 2qt-8  (NOT 2qt-7 — that was round 3's bug).
// ---------------------------------------------------------------------------
__global__ __launch_bounds__(512, 2) void attn_mfma(const f16* __restrict__ QKVh,
                                                    const f16* __restrict__ Kh,
                                                    const f16* __restrict__ Vt,
                                                    f16* __restrict__ attnh) {
    __shared__ __align__(16) f16 sK[2][64 * 256];  // [key][dim], XOR swizzle
    __shared__ __align__(16) f16 sV[2][256 * 64];  // [dim][key], XOR swizzle
    __shared__ __align__(16) f16 sP[8][16 * 72];   // per-wave P, stride 72

    const int qt = blockIdx.x, h = blockIdx.y, b = blockIdx.z;
    const int kvh = h / (H_ / KV_);
    const int t = threadIdx.x, lane = t & 63, w = t >> 6;
    const int i16 = lane & 15, q4 = lane >> 4;

    // Q fragments (A-layout): query row = i16, dims k = kk*32 + q4*8 + j
    const int qrow = qt * 128 + w * 16 + i16;
    const f16* qbase = QKVh + (size_t)(b * S_ + qrow) * 3072 + h * HD_ + q4 * 8;
    half8 qf[8];
#pragma unroll
    for (int kk = 0; kk < 8; ++kk) qf[kk] = *(const half8*)(qbase + kk * 32);

    floatx4 o[16];
#pragma unroll
    for (int i = 0; i < 16; ++i) o[i] = (floatx4){0.f, 0.f, 0.f, 0.f};
    float mrow[4] = {-1e30f, -1e30f, -1e30f, -1e30f};
    float lrow[4] = {0.f, 0.f, 0.f, 0.f};

    const size_t kbase = (size_t)(b * KV_ + kvh) * S_ * HD_;
    const size_t vbase = (size_t)(b * KV_ + kvh) * HD_ * S_;
    const int srow0 = qt * 128 + w * 16 + q4 * 4;

    // block-level and wave-level kt ranges
    const int kt_lo = (2 * qt - 8) > 0 ? (2 * qt - 8) : 0;
    const int kt_hi = 2 * qt + 1;
    const int s_lo_w = qt * 128 + w * 16;
    int ktw_lo = (s_lo_w - (WINDOW_ - 1)) >> 6;
    if (ktw_lo < kt_lo) ktw_lo = kt_lo;
    const int ktw_hi = (s_lo_w + 15) >> 6;

    auto stage = [&](int kt, int buf) {
#pragma unroll
        for (int c = 0; c < 4; ++c) {
            const int chunk = w * 4 + c;
            const int keyl = chunk * 2 + (lane >> 5);
            const int g = (lane & 31) ^ (keyl & 31);
            GLOAD_LDS16(Kh + kbase + (size_t)(kt * 64 + keyl) * HD_ + g * 8,
                        sK[buf] + chunk * 512 + lane * 8);
            const int diml = chunk * 8 + (lane >> 3);
            const int g2 = (lane & 7) ^ (diml & 7);
            GLOAD_LDS16(Vt + vbase + (size_t)diml * S_ + kt * 64 + g2 * 8,
                        sV[buf] + chunk * 512 + lane * 8);
        }
    };

    stage(kt_lo, 0);
    int cur = 0;
    for (int kt = kt_lo; kt <= kt_hi; ++kt, cur ^= 1) {
        __syncthreads();  // drains this wave's loads for buf `cur`, syncs all
        if (kt < kt_hi) stage(kt + 1, cur ^ 1);
        if (kt < ktw_lo || kt > ktw_hi) continue;

        const f16* sKc = sK[cur];
        const f16* sVc = sV[cur];

        // ---- QK^T: scores[16q x 64k] per wave ----
        floatx4 sc[4];
#pragma unroll
        for (int nt = 0; nt < 4; ++nt) sc[nt] = (floatx4){0.f, 0.f, 0.f, 0.f};
#pragma unroll
        for (int ks = 0; ks < 8; ++ks)
#pragma unroll
            for (int nt = 0; nt < 4; ++nt) {
                const int keyl = nt * 16 + i16;
                const int gp = (ks * 4 + q4) ^ (keyl & 31);
                half8 kf = *(const half8*)(sKc + keyl * 256 + gp * 8);
                sc[nt] = __builtin_amdgcn_mfma_f32_16x16x32_f16(qf[ks], kf, sc[nt], 0, 0, 0);
            }

        // ---- mask + online softmax ----
#pragma unroll
        for (int r = 0; r < 4; ++r) {
            const int s = srow0 + r;
            float mx = -1e30f;
#pragma unroll
            for (int nt = 0; nt < 4; ++nt) {
                const int j = kt * 64 + nt * 16 + i16;
                const bool valid = (j <= s) && (s - j < WINDOW_);
                const float v = valid ? sc[nt][r] : MASKV_;
                sc[nt][r] = v;
                mx = fmaxf(mx, v);
            }
#pragma unroll
            for (int off = 1; off < 16; off <<= 1) mx = fmaxf(mx, __shfl_xor(mx, off));
            const float mnew = fmaxf(mrow[r], mx);
            const float alpha = __expf(mrow[r] - mnew);
            mrow[r] = mnew;
            float rs = 0.f;
#pragma unroll
            for (int nt = 0; nt < 4; ++nt) {
                const float p = __expf(sc[nt][r] - mnew);
                sc[nt][r] = p;
                rs += p;
            }
#pragma unroll
            for (int off = 1; off < 16; off <<= 1) rs += __shfl_xor(rs, off);
            lrow[r] = lrow[r] * alpha + rs;
#pragma unroll
            for (int nt2 = 0; nt2 < 16; ++nt2) o[nt2][r] *= alpha;
        }

        // ---- P: C-layout -> LDS -> A-layout (wave-local) ----
        f16* sPw = sP[w];
#pragma unroll
        for (int nt = 0; nt < 4; ++nt)
#pragma unroll
            for (int r = 0; r < 4; ++r)
                sPw[(q4 * 4 + r) * 72 + nt * 16 + i16] = (f16)sc[nt][r];
        asm volatile("s_waitcnt lgkmcnt(0)" ::: "memory");

        // ---- PV: o[16q x 256d] += P[16q x 64k] @ V[64k x 256d] ----
#pragma unroll
        for (int kt2 = 0; kt2 < 2; ++kt2) {
            half8 pf = *(const half8*)(sPw + i16 * 72 + kt2 * 32 + q4 * 8);
#pragma unroll
            for (int nt2 = 0; nt2 < 16; ++nt2) {
                const int dim = nt2 * 16 + i16;
                const int gp = (kt2 * 4 + q4) ^ (dim & 7);
                half8 vf = *(const half8*)(sVc + dim * 64 + gp * 8);
                o[nt2] = __builtin_amdgcn_mfma_f32_16x16x32_f16(pf, vf, o[nt2], 0, 0, 0);
            }
        }
    }

    // ---- epilogue ----
    float inv[4];
#pragma unroll
    for (int r = 0; r < 4; ++r) inv[r] = 1.0f / lrow[r];
    f16* ob = attnh + (size_t)(b * S_ + qt * 128 + w * 16) * (H_ * HD_) + h * HD_;
#pragma unroll
    for (int nt2 = 0; nt2 < 16; ++nt2)
#pragma unroll
        for (int r = 0; r < 4; ++r)
            ob[(size_t)(q4 * 4 + r) * (H_ * HD_) + nt2 * 16 + i16] =
                (f16)(o[nt2][r] * inv[r]);
}

// ---------------------------------------------------------------------------
extern "C" void kernel_launch(void* const* d_in, const int* in_sizes, int n_in,
                              void* d_out, int out_size, void* d_ws, size_t ws_size,
                              hipStream_t stream) {
    const float* x    = (const float*)d_in[0];
    const float* cosb = (const float*)d_in[1];
    const float* sinb = (const float*)d_in[2];
    const float* wq = (const float*)d_in[4];
    const float* wk = (const float*)d_in[5];
    const float* wv = (const float*)d_in[6];
    const float* wo = (const float*)d_in[7];
    const float* qw = (const float*)d_in[8];
    const float* kw = (const float*)d_in[9];
    float* out = (float*)d_out;

    f16* ws = (f16*)d_ws;
    f16* xh    = ws;                       // 8388608 (aliased as attnh later)
    f16* BT    = xh + 8388608;             // 6291456  [3072][2048]
    f16* woT   = BT + 6291456;             // 4194304  [2048][2048]
    f16* QKVh  = woT + 4194304;            // 12582912 [4096][3072]
    f16* Kh    = QKVh + 12582912;          // 2097152
    f16* Vt    = Kh + 2097152;             // 2097152
    f16* attnh = xh;                       // alias: xh dead after QKV GEMM

    const int M = B_ * S_;  // 4096

    // 1) convert x + transpose all weights (one dispatch)
    prep<<<18432, 256, 0, stream>>>(x, wq, wk, wv, wo, xh, BT, woT);

    // 2) fused QKV projection: [4096][2048] @ [3072][2048]^T
    gemm_f16<f16><<<dim3(24, 32), 256, 0, stream>>>(xh, BT, QKVh, M, 3072, D_);

    // 3) RMSNorm + RoPE (+K pack, V transpose)
    norm_rope_f16<<<(B_ * S_ * (H_ + 2 * KV_) * 64) / 256, 256, 0, stream>>>(
        QKVh, Kh, Vt, cosb, sinb, qw, kw);

    // 4) flash attention (128-query tiles, double-buffered staging)
    attn_mfma<<<dim3(S_ / 128, H_, B_), 512, 0, stream>>>(QKVh, Kh, Vt, attnh);

    // 5) output projection (fp32 out)
    gemm_f16<float><<<dim3(16, 32), 256, 0, stream>>>(attnh, woT, out, M, D_, H_ * HD_);
}